// Round 2
// baseline (254.708 us; speedup 1.0000x reference)
//
#include <hip/hip_runtime.h>

#define NNODE  18
#define ROWF2  9                 // float2 per adj row
#define ADJ_F  324               // floats per batch (18*18)
#define ADJ_B  1296              // bytes per batch matrix
#define TILE   31                // batches per block: 31*1296 = 40,176 B LDS -> 4 blocks/CU
#define NWAVE  4                 // 256 threads
#define TILE_BYTES (TILE * ADJ_B)   // 40,176

// Direct global->LDS DMA, 16B per lane per call. LDS dest = uniform base + lane*16 (linear).
#define GLOAD_LDS16(g, l)                                                        \
    __builtin_amdgcn_global_load_lds(                                            \
        (const __attribute__((address_space(1))) void*)(g),                      \
        (__attribute__((address_space(3))) void*)(l), 16, 0, 0)

__global__ __launch_bounds__(256, 4) void gcnn_fused(
    const float* __restrict__ nf,      // [B,18]
    const float* __restrict__ adj,     // [B,18,18]
    const float* __restrict__ proj_w,  // [1]
    const float* __restrict__ proj_b,  // [1]
    const float* __restrict__ w1, const float* __restrict__ b1,   // [10,18],[10]
    const float* __restrict__ w2, const float* __restrict__ b2,   // [8,10],[8]
    const float* __restrict__ w3, const float* __restrict__ b3,   // [2,8],[2]
    float* __restrict__ out,           // [B,2]
    int B)
{
    __shared__ __align__(16) char smem[TILE_BYTES];   // adj tile, LINEAR layout (global_load_lds)
    const int tid  = threadIdx.x;
    const int wave = tid >> 6;
    const int lane = tid & 63;
    const int b0   = blockIdx.x * TILE;
    const int nb   = min(TILE, B - b0);
    const int nbytes = nb * ADJ_B;

    // ---- Stage adj tile: pure DMA, all chunks issued with NO intervening waits ----
    // ceil(40176/1024) = 40 wave-chunks of 1 KiB, round-robined over 4 waves (~10 each).
    const char* __restrict__ gbase = (const char*)adj + (size_t)b0 * ADJ_B;
    for (int c = wave; c * 1024 < nbytes; c += NWAVE) {
        const int off = c * 1024 + lane * 16;
        if (off < nbytes) {                      // multiples of 16: off<nbytes == off+16<=nbytes
            GLOAD_LDS16(gbase + off, smem + c * 1024);
        }
    }
    __syncthreads();   // drains vmcnt(0): whole tile resident

    // ---- Per-thread compute: one batch, both GCN layers from the SAME resident tile ----
    const int b = b0 + tid;                      // threads 0..nb-1 compute
    if (tid < nb) {
        const float pw = proj_w[0], pb = proj_b[0];
        const float* __restrict__ my = (const float*)smem + tid * ADJ_F;

        // node features: 72 B/thread; consecutive threads cover a contiguous span
        float x[NNODE];
        const float2* __restrict__ nfp = (const float2*)(nf + (size_t)b * NNODE);
        #pragma unroll
        for (int j = 0; j < ROWF2; ++j) { float2 v = nfp[j]; x[2*j] = v.x; x[2*j+1] = v.y; }

        // Layer 1: deg (row-sum) + matvec in one sweep.
        // h = relu( w*(A x)/deg + pb )  since A*1 = deg and proj is 1x1
        float invd[NNODE], h[NNODE];
        #pragma unroll
        for (int n = 0; n < NNODE; ++n) {
            const float2* __restrict__ row = (const float2*)(my + n * NNODE);
            float d = 0.f, s = 0.f;
            #pragma unroll
            for (int m = 0; m < ROWF2; ++m) {
                float2 a = row[m];               // ds_read_b64
                d += a.x + a.y;
                s += a.x * x[2*m] + a.y * x[2*m+1];
            }
            float inv = 1.0f / d;
            invd[n] = inv;
            h[n] = fmaxf(0.f, pw * s * inv + pb);
        }

        // Layer 2: rows re-read from LDS (resident), reuse 1/deg
        float y[NNODE];
        #pragma unroll
        for (int n = 0; n < NNODE; ++n) {
            const float2* __restrict__ row = (const float2*)(my + n * NNODE);
            float s = 0.f;
            #pragma unroll
            for (int m = 0; m < ROWF2; ++m) {
                float2 a = row[m];
                s += a.x * h[2*m] + a.y * h[2*m+1];
            }
            float v = fmaxf(0.f, pw * s * invd[n] + pb);
            y[n] = (v != v) ? 0.f : v;           // NaN scrub (matches reference)
        }

        // MLP head: weight addresses are thread-uniform -> scalar loads, cache-served
        float z1[10];
        #pragma unroll
        for (int k = 0; k < 10; ++k) {
            float s = b1[k];
            #pragma unroll
            for (int j = 0; j < NNODE; ++j) s += w1[k*NNODE + j] * y[j];
            z1[k] = fmaxf(0.f, s);
        }
        float z2[8];
        #pragma unroll
        for (int k = 0; k < 8; ++k) {
            float s = b2[k];
            #pragma unroll
            for (int j = 0; j < 10; ++j) s += w2[k*10 + j] * z1[j];
            z2[k] = fmaxf(0.f, s);
        }
        float o0 = b3[0], o1 = b3[1];
        #pragma unroll
        for (int j = 0; j < 8; ++j) { o0 += w3[j] * z2[j]; o1 += w3[8 + j] * z2[j]; }

        *(float2*)(out + (size_t)b * 2) = make_float2(o0, o1);   // contiguous 8B stores
    }
}

extern "C" void kernel_launch(void* const* d_in, const int* in_sizes, int n_in,
                              void* d_out, int out_size, void* d_ws, size_t ws_size,
                              hipStream_t stream) {
    const float* nf  = (const float*)d_in[0];
    const float* adj = (const float*)d_in[1];
    const float* pw  = (const float*)d_in[2];
    const float* pb  = (const float*)d_in[3];
    const float* w1  = (const float*)d_in[4];
    const float* b1  = (const float*)d_in[5];
    const float* w2  = (const float*)d_in[6];
    const float* b2  = (const float*)d_in[7];
    const float* w3  = (const float*)d_in[8];
    const float* b3  = (const float*)d_in[9];
    float* out = (float*)d_out;

    const int B = in_sizes[0] / NNODE;              // 131072
    const int grid = (B + TILE - 1) / TILE;         // 4229 blocks

    gcnn_fused<<<grid, 256, 0, stream>>>(nf, adj, pw, pb, w1, b1, w2, b2, w3, b3, out, B);
}

// Round 3
// 63.425 us; speedup vs baseline: 4.0159x; 4.0159x over previous
//
#include <hip/hip_runtime.h>

#define NNODE  18
#define ROWF2  9                 // float2 per adj row
#define ADJ_F  324               // floats per batch (18*18)
#define ADJ_B  1296              // bytes per batch matrix (81 x 16B chunks)
#define TILE   61                // batches per block: 61*1296 = 79,056 B LDS -> 2 blocks/CU
#define TILE_BYTES (TILE * ADJ_B)

// Direct global->LDS DMA, 16B per lane. LDS dest = wave-uniform base (+ lane*16 in HW).
#define GLOAD_LDS16(g, l)                                                        \
    __builtin_amdgcn_global_load_lds(                                            \
        (const __attribute__((address_space(1))) void*)(g),                      \
        (__attribute__((address_space(3))) void*)(l), 16, 0, 0)

__global__ __launch_bounds__(64, 1) void gcnn_fused(
    const float* __restrict__ nf,      // [B,18]
    const float* __restrict__ adj,     // [B,18,18]
    const float* __restrict__ proj_w,  // [1]
    const float* __restrict__ proj_b,  // [1]
    const float* __restrict__ w1, const float* __restrict__ b1,   // [10,18],[10]
    const float* __restrict__ w2, const float* __restrict__ b2,   // [8,10],[8]
    const float* __restrict__ w3, const float* __restrict__ b3,   // [2,8],[2]
    float* __restrict__ out,           // [B,2]
    int B)
{
    extern __shared__ __align__(16) char smem[];   // TILE_BYTES, LINEAR (global_load_lds)
    const int lane = threadIdx.x;                  // block = 1 wave
    const int b0   = blockIdx.x * TILE;
    const int nb   = min(TILE, B - b0);
    const int nbytes = nb * ADJ_B;

    // ---- Prefetch node features into regs (independent of DMA; latency hides under it) ----
    const int b = b0 + lane;
    float x[NNODE];
    if (lane < nb) {
        const float2* __restrict__ nfp = (const float2*)(nf + (size_t)b * NNODE);
        #pragma unroll
        for (int j = 0; j < ROWF2; ++j) { float2 v = nfp[j]; x[2*j] = v.x; x[2*j+1] = v.y; }
    }

    // ---- Stage adj tile: pure DMA, 78 x 1KiB chunks, no waits until barrier ----
    const char* __restrict__ gbase = (const char*)adj + (size_t)b0 * ADJ_B;
    for (int c = 0; c * 1024 < nbytes; ++c) {
        const int off = c * 1024 + lane * 16;
        if (off < nbytes) {                        // 16B-multiples: off<nbytes == off+16<=nbytes
            GLOAD_LDS16(gbase + off, smem + c * 1024);
        }
    }
    __syncthreads();   // drains vmcnt(0): tile resident

    // ---- Per-thread compute: one batch, both GCN layers from the SAME resident tile ----
    if (lane < nb) {
        const float pw = proj_w[0], pb = proj_b[0];
        const float* __restrict__ my = (const float*)smem + lane * ADJ_F;

        // Layer 1: deg (row-sum) + matvec in one sweep.
        // h = relu( w*(A x)/deg + pb )  since A*1 = deg and proj is 1x1
        float invd[NNODE], h[NNODE];
        #pragma unroll
        for (int n = 0; n < NNODE; ++n) {
            const float2* __restrict__ row = (const float2*)(my + n * NNODE);
            float d = 0.f, s = 0.f;
            #pragma unroll
            for (int m = 0; m < ROWF2; ++m) {
                float2 a = row[m];                 // ds_read_b64 (8-way conflict, accepted)
                d += a.x + a.y;
                s += a.x * x[2*m] + a.y * x[2*m+1];
            }
            float inv = 1.0f / d;
            invd[n] = inv;
            h[n] = fmaxf(0.f, pw * s * inv + pb);
        }

        // Layer 2: rows re-read from LDS (resident), reuse 1/deg
        float y[NNODE];
        #pragma unroll
        for (int n = 0; n < NNODE; ++n) {
            const float2* __restrict__ row = (const float2*)(my + n * NNODE);
            float s = 0.f;
            #pragma unroll
            for (int m = 0; m < ROWF2; ++m) {
                float2 a = row[m];
                s += a.x * h[2*m] + a.y * h[2*m+1];
            }
            float v = fmaxf(0.f, pw * s * invd[n] + pb);
            y[n] = (v != v) ? 0.f : v;             // NaN scrub (matches reference)
        }

        // MLP head: weight addresses are lane-uniform -> scalar/broadcast loads
        float z1[10];
        #pragma unroll
        for (int k = 0; k < 10; ++k) {
            float s = b1[k];
            #pragma unroll
            for (int j = 0; j < NNODE; ++j) s += w1[k*NNODE + j] * y[j];
            z1[k] = fmaxf(0.f, s);
        }
        float z2[8];
        #pragma unroll
        for (int k = 0; k < 8; ++k) {
            float s = b2[k];
            #pragma unroll
            for (int j = 0; j < 10; ++j) s += w2[k*10 + j] * z1[j];
            z2[k] = fmaxf(0.f, s);
        }
        float o0 = b3[0], o1 = b3[1];
        #pragma unroll
        for (int j = 0; j < 8; ++j) { o0 += w3[j] * z2[j]; o1 += w3[8 + j] * z2[j]; }

        *(float2*)(out + (size_t)b * 2) = make_float2(o0, o1);   // contiguous 8B stores
    }
}

extern "C" void kernel_launch(void* const* d_in, const int* in_sizes, int n_in,
                              void* d_out, int out_size, void* d_ws, size_t ws_size,
                              hipStream_t stream) {
    const float* nf  = (const float*)d_in[0];
    const float* adj = (const float*)d_in[1];
    const float* pw  = (const float*)d_in[2];
    const float* pb  = (const float*)d_in[3];
    const float* w1  = (const float*)d_in[4];
    const float* b1  = (const float*)d_in[5];
    const float* w2  = (const float*)d_in[6];
    const float* b2  = (const float*)d_in[7];
    const float* w3  = (const float*)d_in[8];
    const float* b3  = (const float*)d_in[9];
    float* out = (float*)d_out;

    const int B = in_sizes[0] / NNODE;              // 131072
    const int grid = (B + TILE - 1) / TILE;         // 2149 blocks

    hipFuncSetAttribute(reinterpret_cast<const void*>(gcnn_fused),
                        hipFuncAttributeMaxDynamicSharedMemorySize, TILE_BYTES);

    gcnn_fused<<<grid, 64, TILE_BYTES, stream>>>(nf, adj, pw, pb, w1, b1, w2, b2, w3, b3, out, B);
}